// Round 13
// baseline (936.006 us; speedup 1.0000x reference)
//
#include <hip/hip_runtime.h>

// Multi-layer tanh RNN, layer-pipelined persistent kernel.
// R29 = R28 (best, 883us) + MFMA chain-depth 4 -> 2:
//  R28's -830cyc/step for ~150cyc of removed issue proves the step is
//  dependency-LATENCY-bound (2 waves/SIMD, phase-locked -> latencies only
//  half-hidden). So: split each 4-deep accumulator chain into 2x2-deep
//  (aL/aH seeded {bias,0}, cL/cH; kc pairs (0,1)/(2,3)), 8 independent
//  2-deep chains total (+16 VGPR, +2 f32x4 adds/ntl), and fuse the
//  epilogue per-ntl so ntl0's tanh/writes overlap ntl1's MFMAs.
//  Bank-conflict note: A-frag b128 reads compute to the conflict-free
//  minimum (8 lane-groups x 4 banks); the 2.1e7 counter is the scattered
//  b16 epilogue writes (~256cyc/block-step) - not the wall.
//  K=4 rejected this round: fill -24us but 2x upub frequency + per-preb
//  flag-load latency ~cancels.
// Everything else = R28: single-plane RTN bf16 weights, boundary
// pipelining (preb flag waits + prologue slot-0 staging), m-major [16][128]
// ring, b128 staging, producer-from-settled-hbufU deferred-by-2,
// bias-in-acc, col-100 out fold, K=8/RD=32, layer-pair blocks NT=512.

#define HH   100   // hidden
#define HS   132   // padded fp32 stride (bias etc.)
#define HSS  136   // bf16 LDS row stride in shorts (272B = 17*16, b128-aligned)
#define NL   10    // layers
#define NPAIR 5    // layer pairs per chunk
#define NIF   4    // global ring interfaces (between pairs)
#define BBS  512   // batch
#define TTS  512   // time
#define NB   32    // batch chunks
#define BC   16    // batch per chunk
#define NT   512   // threads per block (8 waves: 0-3 lower, 4-7 upper)
#define SLOTS (BC * 128)   // ring slot: m-major [16][128] bf16 = 2048 shorts

typedef __attribute__((ext_vector_type(8))) short short8;
typedef __attribute__((ext_vector_type(4))) float f32x4;
typedef __attribute__((ext_vector_type(4))) unsigned int u32x4;

__global__ void init_ws_kernel(int* wsi) {
  int i = blockIdx.x * blockDim.x + threadIdx.x;
  if (i < 16384) wsi[i] = 0;   // zero both flag regions (64KB)
}

__device__ __forceinline__ int flag_idx(int iface, int chunk) {
  return (iface * NB + chunk) * 16;
}

__device__ __forceinline__ void lds_barrier() {
  __asm__ __volatile__("s_waitcnt lgkmcnt(0)\n\ts_barrier" ::: "memory");
}
__device__ __forceinline__ void ctl_barrier() {
  __asm__ __volatile__("s_barrier" ::: "memory");
}

__device__ __forceinline__ float fast_tanh(float v) {
  float e = __expf(2.0f * v);
  return 1.0f - 2.0f * __builtin_amdgcn_rcpf(e + 1.0f);
}

__device__ __forceinline__ unsigned short bf_rtn(float x) {
  return (unsigned short)((__float_as_uint(x) + 0x8000u) >> 16);
}

__global__ __launch_bounds__(NT, 1) void rnn_pipe(
    const float* __restrict__ x,     // [B,T,1]
    const float* __restrict__ h0,    // [L,B,H]
    const float* __restrict__ Wih0,  // [H,1]
    const float* __restrict__ Wih,   // [L-1,H,H]
    const float* __restrict__ Whh,   // [L,H,H]
    const float* __restrict__ bih,   // [L,H]
    const float* __restrict__ bhh,   // [L,H]
    const float* __restrict__ Wout,  // [1,H]
    const float* __restrict__ bout,  // [1]
    float* __restrict__ out,         // [B*T] outs ++ [L*B*H] h_final
    unsigned short* __restrict__ ring,
    int*   __restrict__ wsi,
    int Kv, int RDv)
{
  const int pair  = blockIdx.x / NB;
  const int chunk = blockIdx.x % NB;
  const int tid   = threadIdx.x;
  const int grp   = tid >> 8;          // 0 = lower layer (2p), 1 = upper (2p+1)
  const int wtid  = tid & 255;
  const int layer = pair * 2 + grp;
  const int Km = Kv - 1, RDm = RDv - 1;
  const int NE = BC * HH;  // 1600 elements per activation slot

  const int wave = wtid >> 6, lane = wtid & 63;
  const int quad = lane >> 4, lp = lane & 15;
  const bool is_l9 = (grp == 1 && pair == NPAIR - 1);

  // LDS: 3 state buffers (26.1KB) + consts (~2.3KB)
  __shared__ unsigned short hbufL[2][BC][HSS];  // lower recurrent state bf16
  __shared__ unsigned short hbufU[2][BC][HSS];  // upper recurrent state bf16
  __shared__ unsigned short ibufL[2][BC][HSS];  // lower ring-staged input bf16
  __shared__ float biasS[2][HS];
  __shared__ float wi0s[HS];
  __shared__ float wouts[HS];
  __shared__ float xin[2][BC];

  // ---- one-time LDS init ----
  for (int i = tid; i < 2 * BC * HSS; i += NT) {
    (&hbufL[0][0][0])[i] = 0; (&hbufU[0][0][0])[i] = 0; (&ibufL[0][0][0])[i] = 0;
  }
  for (int i = wtid; i < HS; i += 256) {
    float bv = 0.f;
    if (i < HH) bv = bih[layer * HH + i] + bhh[layer * HH + i];
    else if (i == 100 && layer == NL - 1) bv = bout[0];   // col-100 bias
    biasS[grp][i] = bv;
    if (grp == 0) wi0s[i]  = (i < HH) ? Wih0[i] : 0.f;
    else          wouts[i] = (i < HH) ? Wout[i] : 0.f;
  }
  if (tid < BC) { xin[0][tid] = 0.f; xin[1][tid] = 0.f; }
  __syncthreads();
  // h0: lower reads at s=0 from [par=0]; upper reads at s=1 from [par=1]
  for (int idx = wtid; idx < NE; idx += 256) {
    unsigned short v =
        bf_rtn(h0[((size_t)layer * BBS + chunk * BC + idx / HH) * HH + idx % HH]);
    if (grp == 0) hbufL[0][idx / HH][idx % HH] = v;
    else          hbufU[1][idx / HH][idx % HH] = v;
  }

  // ---- B-fragments: fused W = [Whh (k 0..99) ; Wih (k 128..227)],
  // SINGLE-PLANE RTN bf16. For layer 9, n==100 carries Wout in the Whh half.
  short8 Bf[8][2];
  #pragma unroll
  for (int kc = 0; kc < 8; ++kc) {
    #pragma unroll
    for (int ntl = 0; ntl < 2; ++ntl) {
      const int n = wave * 32 + ntl * 16 + lp;
      float wv[8];
      #pragma unroll
      for (int j = 0; j < 8; ++j) {
        const int k = kc * 32 + quad * 8 + j;
        float w = 0.f;
        if (kc < 4) {
          if (k < HH) {
            if (n < HH) w = Whh[(size_t)layer * HH * HH + n * HH + k];
            else if (n == 100 && layer == NL - 1) w = Wout[k];
          }
        } else {
          const int kk = k - 128;
          if (layer > 0 && kk >= 0 && kk < HH && n < HH)
            w = Wih[(size_t)(layer - 1) * HH * HH + n * HH + kk];
        }
        wv[j] = w;
      }
      __attribute__((ext_vector_type(4))) unsigned int p1;
      #pragma unroll
      for (int j2 = 0; j2 < 4; ++j2)
        p1[j2] = (unsigned)bf_rtn(wv[2 * j2]) | ((unsigned)bf_rtn(wv[2 * j2 + 1]) << 16);
      Bf[kc][ntl] = __builtin_bit_cast(short8, p1);
    }
  }

  // ---- flags / ring pointers: 4 cross-pair interfaces, R19 protocol ----
  const bool is_cons = (grp == 0 && pair > 0);            // lower consumes ring
  const bool is_prod = (grp == 1 && pair < NPAIR - 1);    // upper produces ring
  int* prog_in  = is_cons ? wsi + flag_idx(pair - 1, chunk)        : nullptr;
  int* cons_in  = is_cons ? wsi + 8192 + flag_idx(pair - 1, chunk) : nullptr;
  int* prog_out = is_prod ? wsi + flag_idx(pair, chunk)            : nullptr;
  int* cons_out = is_prod ? wsi + 8192 + flag_idx(pair, chunk)     : nullptr;
  unsigned short* ring_in  = is_cons ? ring + (size_t)((pair - 1) * NB + chunk) * RDv * SLOTS : nullptr;
  unsigned short* ring_out = is_prod ? ring + (size_t)(pair * NB + chunk) * RDv * SLOTS       : nullptr;

  const int jcv[2] = { wave * 32 + lp, wave * 32 + 16 + lp };   // C columns
  const float br[2]  = { biasS[grp][jcv[0]], biasS[grp][jcv[1]] };
  const float w0r[2] = { wi0s[jcv[0]], wi0s[jcv[1]] };
  const float boutv = bout[0];

  f32x4 hreg[2] = {};        // my h(t) fp32 (h_final exactness)
  float px = 0.f;
  const int srow = wtid >> 4, scol = (wtid & 15) * 8;   // staging coords

  // ---- prologue: slot-0 wait + exposed staging (once) ----
  if (tid == 0 && is_cons) {
    while (__hip_atomic_load(prog_in, __ATOMIC_RELAXED, __HIP_MEMORY_SCOPE_AGENT) < Kv)
      __builtin_amdgcn_s_sleep(1);
    (void)__hip_atomic_load(prog_in, __ATOMIC_ACQUIRE, __HIP_MEMORY_SCOPE_AGENT);
  }
  ctl_barrier();
  if (is_cons) {
    u32x4 g = *(const u32x4*)(ring_in + wtid * 8);   // slot 0
    *(u32x4*)&ibufL[0][srow][scol] = g;
  }
  if (grp == 0 && pair == 0 && wtid < BC)
    xin[0][wtid] = x[(size_t)(chunk * BC + wtid) * TTS];
  __syncthreads();

  for (int s = 0; s <= TTS; ++s) {
    const int par = s & 1, nxt = par ^ 1;
    const bool active = (grp == 0) ? (s < TTS) : (s >= 1);
    const int t = (grp == 0) ? s : s - 1;          // my timestep this step
    const bool preb = ((s & Km) == Km) && (s + 1 < TTS);   // pre-boundary
    const bool upub = (s >= 1) && ((s & Km) == 0);         // publish steps

    // ---- pre-boundary: flag waits for batch [s+1, s+1+K) ----
    if (preb) {
      if (tid == 0 && is_cons) {
        while (__hip_atomic_load(prog_in, __ATOMIC_RELAXED, __HIP_MEMORY_SCOPE_AGENT) < s + 1 + Kv)
          __builtin_amdgcn_s_sleep(1);
        (void)__hip_atomic_load(prog_in, __ATOMIC_ACQUIRE, __HIP_MEMORY_SCOPE_AGENT);
      }
      if (tid == 256 && is_prod && s + 1 + Kv > RDv) {
        while (__hip_atomic_load(cons_out, __ATOMIC_RELAXED, __HIP_MEMORY_SCOPE_AGENT) < s + 1 + Kv - RDv)
          __builtin_amdgcn_s_sleep(1);
      }
      ctl_barrier();
    }

    // ---- producer deferred ring store: slot s-2 from SETTLED hbufU[par] ----
    if (is_prod && s >= 2 && ((s - 1) & Km) != 0) {
      u32x4 v = *(const u32x4*)&hbufU[par][srow][scol];
      *(u32x4*)(ring_out + (size_t)((s - 2) & RDm) * SLOTS + wtid * 8) = v;
    }

    // ---- prefetch load: slot s+1 -> regs (staged into ibufL[nxt] late) ----
    u32x4 pv = {};
    bool pre = false;
    if (is_cons && s + 1 < TTS) {
      pv = *(const u32x4*)(ring_in + (size_t)((s + 1) & RDm) * SLOTS + wtid * 8);
      pre = true;
    }
    if (grp == 0 && pair == 0 && s + 1 < TTS && wtid < BC)
      px = x[(size_t)(chunk * BC + wtid) * TTS + (s + 1)];

    if (active) {
      // ---- A-fragments: hoisted LDS reads ----
      const unsigned short (*myH)[HSS] = (grp == 0) ? hbufL[par] : hbufU[par];
      const unsigned short (*myI)[HSS] = (grp == 0) ? ibufL[par] : hbufL[par];
      short8 Ah[4], AiS[4];
      #pragma unroll
      for (int kc = 0; kc < 4; ++kc)
        Ah[kc] = *(const short8*)&myH[lp][kc * 32 + quad * 8];
      const bool has_in = (grp == 1) || (pair > 0);
      if (has_in) {
        #pragma unroll
        for (int kc = 0; kc < 4; ++kc)
          AiS[kc] = *(const short8*)&myI[lp][kc * 32 + quad * 8];
      } else {
        #pragma unroll
        for (int kc = 0; kc < 4; ++kc) AiS[kc] = short8{};
      }

      // ---- MFMA: 2+2-deep split chains, per-ntl fused epilogue ----
      unsigned short (*myHn)[HSS] = (grp == 0) ? hbufL[nxt] : hbufU[nxt];
      #pragma unroll
      for (int ntl = 0; ntl < 2; ++ntl) {
        f32x4 aL = (f32x4){br[ntl], br[ntl], br[ntl], br[ntl]};
        f32x4 aH = {}, cL = {}, cH = {};
        if (has_in) {
          cL = __builtin_amdgcn_mfma_f32_16x16x32_bf16(AiS[0], Bf[4][ntl], cL, 0, 0, 0);
          cH = __builtin_amdgcn_mfma_f32_16x16x32_bf16(AiS[2], Bf[6][ntl], cH, 0, 0, 0);
          cL = __builtin_amdgcn_mfma_f32_16x16x32_bf16(AiS[1], Bf[5][ntl], cL, 0, 0, 0);
          cH = __builtin_amdgcn_mfma_f32_16x16x32_bf16(AiS[3], Bf[7][ntl], cH, 0, 0, 0);
        }
        aL = __builtin_amdgcn_mfma_f32_16x16x32_bf16(Ah[0], Bf[0][ntl], aL, 0, 0, 0);
        aH = __builtin_amdgcn_mfma_f32_16x16x32_bf16(Ah[2], Bf[2][ntl], aH, 0, 0, 0);
        aL = __builtin_amdgcn_mfma_f32_16x16x32_bf16(Ah[1], Bf[1][ntl], aL, 0, 0, 0);
        aH = __builtin_amdgcn_mfma_f32_16x16x32_bf16(Ah[3], Bf[3][ntl], aH, 0, 0, 0);
        f32x4 sum = (aL + aH) + (cL + cH);
        #pragma unroll
        for (int r = 0; r < 4; ++r) {
          const int m = quad * 4 + r;
          float v = sum[r];
          if (layer == 0) v += xin[par][m] * w0r[ntl];
          if (is_l9 && jcv[ntl] == 100) {
            if (s >= 2)
              out[(size_t)(chunk * BC + m) * TTS + (s - 2)] = v;  // bias==bout
          } else {
            float h = fast_tanh(v);
            hreg[ntl][r] = h;
            if (jcv[ntl] < HH) myHn[m][jcv[ntl]] = bf_rtn(h);
          }
        }
      }

      if (t == TTS - 1) {   // final hidden state, fp32-exact from registers
        #pragma unroll
        for (int ntl = 0; ntl < 2; ++ntl)
          if (jcv[ntl] < HH)
            #pragma unroll
            for (int r = 0; r < 4; ++r)
              out[(size_t)BBS * TTS +
                  ((size_t)layer * BBS + chunk * BC + quad * 4 + r) * HH + jcv[ntl]] =
                  hreg[ntl][r];
      }
    }

    // ---- stage prefetched slot s+1 into ibufL[nxt] (one b128 write) ----
    if (pre) *(u32x4*)&ibufL[nxt][srow][scol] = pv;
    if (grp == 0 && pair == 0 && s + 1 < TTS && wtid < BC) xin[nxt][wtid] = px;

    // ---- end-of-step barrier (+ batch-last store & publish at upub) ----
    if (upub) {
      lds_barrier();           // settle hbufU[nxt] for the in-step store
      if (is_prod) {           // batch-last slot s-1, coalesced from LDS
        u32x4 v = *(const u32x4*)&hbufU[nxt][srow][scol];
        *(u32x4*)(ring_out + (size_t)((s - 1) & RDm) * SLOTS + wtid * 8) = v;
      }
      __syncthreads();         // full drain: all ring stores visible pre-flag
      if (tid == 256 && is_prod)
        __hip_atomic_store(prog_out, s, __ATOMIC_RELEASE, __HIP_MEMORY_SCOPE_AGENT);
      if (tid == 0 && is_cons)
        __hip_atomic_store(cons_in, s, __ATOMIC_RELAXED, __HIP_MEMORY_SCOPE_AGENT);
    } else {
      lds_barrier();
    }
  }

  // final output out(TTS-1) = h9(TTS-1)·wout + bout: one-time serial dot
  if (is_l9) {
    const int b = wtid >> 4, seg = wtid & 15;
    float sacc = 0.f;
    #pragma unroll
    for (int jj = 0; jj < 7; ++jj) {
      const int j = seg * 7 + jj;
      if (j < HH) {
        float h = __uint_as_float((unsigned)hbufU[1][b][j] << 16);
        sacc += h * wouts[j];
      }
    }
    sacc += __shfl_xor(sacc, 1, 16);
    sacc += __shfl_xor(sacc, 2, 16);
    sacc += __shfl_xor(sacc, 4, 16);
    sacc += __shfl_xor(sacc, 8, 16);
    if ((wtid & 15) == 0)
      out[(size_t)(chunk * BC + b) * TTS + (TTS - 1)] = sacc + boutv;
  }
}

extern "C" void kernel_launch(void* const* d_in, const int* in_sizes, int n_in,
                              void* d_out, int out_size, void* d_ws, size_t ws_size,
                              hipStream_t stream) {
  const float* x    = (const float*)d_in[0];
  const float* h0   = (const float*)d_in[1];
  const float* Wih0 = (const float*)d_in[2];
  const float* Wih  = (const float*)d_in[3];
  const float* Whh  = (const float*)d_in[4];
  const float* bih  = (const float*)d_in[5];
  const float* bhh  = (const float*)d_in[6];
  const float* Wout = (const float*)d_in[7];
  const float* bout = (const float*)d_in[8];
  float* out = (float*)d_out;

  int* wsi = (int*)d_ws;
  unsigned short* ring = (unsigned short*)((char*)d_ws + 65536);

  // m-major bf16 ring: bytes = 4*32 * RD * 4096 (RD=32 -> 16.8MB).
  const size_t slot_bytes = (size_t)SLOTS * 2;   // 4096
  int RDv = 32;
  while (RDv > 2 && 65536 + (size_t)NIF * NB * RDv * slot_bytes > ws_size)
    RDv >>= 1;
  // DEADLOCK-FREE: skewed pipeline + boundary pipelining needs 2K+1 < RD.
  int Kv = RDv / 4;
  if (Kv < 1) Kv = 1;

  hipLaunchKernelGGL(init_ws_kernel, dim3(64), dim3(256), 0, stream, wsi);
  hipLaunchKernelGGL(rnn_pipe, dim3(NPAIR * NB), dim3(NT), 0, stream,
                     x, h0, Wih0, Wih, Whh, bih, bhh, Wout, bout, out, ring, wsi,
                     Kv, RDv);
}

// Round 14
// 880.563 us; speedup vs baseline: 1.0630x; 1.0630x over previous
//
#include <hip/hip_runtime.h>

// Multi-layer tanh RNN, layer-pipelined persistent kernel.
// R30 = exact revert to R28 (session best, 883us). R29's 2+2-deep chain
// split + per-ntl fused epilogue REGRESSED to 936us: interleaving tanh/
// ds_write between the ntl MFMA groups lengthened the critical path; R28's
// kc-inner/ntl-outer MFMA order (4 naturally interleaved chains) + single
// block epilogue is the schedule-family optimum at 2 waves/SIMD.
// Ladder: 1371 (R16 entry) -> 1200 (R22 layer-pair blocks) -> 1108 (R23
// j-major ring + col-100 out fold) -> 1056 (R27 m-major ring, b128 staging)
// -> 883 (R28 single-plane weights + boundary pipelining).
// R28 design:
//  - Layer-pair blocks (NT=512, grid 5x32): waves 0-3 = layer 2p, 4-7 =
//    2p+1, skewed one step; intra-pair handoff LDS-direct via hbufL.
//  - Single-plane RTN bf16 weights; fused W=[Whh|Wih] K=256 A-layout.
//  - Bias pre-loaded into MFMA accumulator; layer-9 Wout folded into
//    column 100 (bias=bout) -> per-step output comes out of the MFMA.
//  - m-major [16][128] bf16 ring (4KB slots); consumer stages via one
//    contiguous ds_write_b128/thread; producer stores from SETTLED
//    hbufU[par] (deferred-by-2), coalesced dwordx4.
//  - Boundary pipelining: flag waits at pre-boundary step; distance-1
//    prefetch crosses batch boundaries; slot-0 staged in prologue.
//  - K=8/RD=32 (2K+1<RD deadlock-free), R19 agent-scope flag protocol.

#define HH   100   // hidden
#define HS   132   // padded fp32 stride (bias etc.)
#define HSS  136   // bf16 LDS row stride in shorts (272B = 17*16, b128-aligned)
#define NL   10    // layers
#define NPAIR 5    // layer pairs per chunk
#define NIF   4    // global ring interfaces (between pairs)
#define BBS  512   // batch
#define TTS  512   // time
#define NB   32    // batch chunks
#define BC   16    // batch per chunk
#define NT   512   // threads per block (8 waves: 0-3 lower, 4-7 upper)
#define SLOTS (BC * 128)   // ring slot: m-major [16][128] bf16 = 2048 shorts

typedef __attribute__((ext_vector_type(8))) short short8;
typedef __attribute__((ext_vector_type(4))) float f32x4;
typedef __attribute__((ext_vector_type(4))) unsigned int u32x4;

__global__ void init_ws_kernel(int* wsi) {
  int i = blockIdx.x * blockDim.x + threadIdx.x;
  if (i < 16384) wsi[i] = 0;   // zero both flag regions (64KB)
}

__device__ __forceinline__ int flag_idx(int iface, int chunk) {
  return (iface * NB + chunk) * 16;
}

__device__ __forceinline__ void lds_barrier() {
  __asm__ __volatile__("s_waitcnt lgkmcnt(0)\n\ts_barrier" ::: "memory");
}
__device__ __forceinline__ void ctl_barrier() {
  __asm__ __volatile__("s_barrier" ::: "memory");
}

__device__ __forceinline__ float fast_tanh(float v) {
  float e = __expf(2.0f * v);
  return 1.0f - 2.0f * __builtin_amdgcn_rcpf(e + 1.0f);
}

__device__ __forceinline__ unsigned short bf_rtn(float x) {
  return (unsigned short)((__float_as_uint(x) + 0x8000u) >> 16);
}

__global__ __launch_bounds__(NT, 1) void rnn_pipe(
    const float* __restrict__ x,     // [B,T,1]
    const float* __restrict__ h0,    // [L,B,H]
    const float* __restrict__ Wih0,  // [H,1]
    const float* __restrict__ Wih,   // [L-1,H,H]
    const float* __restrict__ Whh,   // [L,H,H]
    const float* __restrict__ bih,   // [L,H]
    const float* __restrict__ bhh,   // [L,H]
    const float* __restrict__ Wout,  // [1,H]
    const float* __restrict__ bout,  // [1]
    float* __restrict__ out,         // [B*T] outs ++ [L*B*H] h_final
    unsigned short* __restrict__ ring,
    int*   __restrict__ wsi,
    int Kv, int RDv)
{
  const int pair  = blockIdx.x / NB;
  const int chunk = blockIdx.x % NB;
  const int tid   = threadIdx.x;
  const int grp   = tid >> 8;          // 0 = lower layer (2p), 1 = upper (2p+1)
  const int wtid  = tid & 255;
  const int layer = pair * 2 + grp;
  const int Km = Kv - 1, RDm = RDv - 1;
  const int NE = BC * HH;  // 1600 elements per activation slot

  const int wave = wtid >> 6, lane = wtid & 63;
  const int quad = lane >> 4, lp = lane & 15;
  const bool is_l9 = (grp == 1 && pair == NPAIR - 1);

  // LDS: 3 state buffers (26.1KB) + consts (~2.3KB)
  __shared__ unsigned short hbufL[2][BC][HSS];  // lower recurrent state bf16
  __shared__ unsigned short hbufU[2][BC][HSS];  // upper recurrent state bf16
  __shared__ unsigned short ibufL[2][BC][HSS];  // lower ring-staged input bf16
  __shared__ float biasS[2][HS];
  __shared__ float wi0s[HS];
  __shared__ float wouts[HS];
  __shared__ float xin[2][BC];

  // ---- one-time LDS init ----
  for (int i = tid; i < 2 * BC * HSS; i += NT) {
    (&hbufL[0][0][0])[i] = 0; (&hbufU[0][0][0])[i] = 0; (&ibufL[0][0][0])[i] = 0;
  }
  for (int i = wtid; i < HS; i += 256) {
    float bv = 0.f;
    if (i < HH) bv = bih[layer * HH + i] + bhh[layer * HH + i];
    else if (i == 100 && layer == NL - 1) bv = bout[0];   // col-100 bias
    biasS[grp][i] = bv;
    if (grp == 0) wi0s[i]  = (i < HH) ? Wih0[i] : 0.f;
    else          wouts[i] = (i < HH) ? Wout[i] : 0.f;
  }
  if (tid < BC) { xin[0][tid] = 0.f; xin[1][tid] = 0.f; }
  __syncthreads();
  // h0: lower reads at s=0 from [par=0]; upper reads at s=1 from [par=1]
  for (int idx = wtid; idx < NE; idx += 256) {
    unsigned short v =
        bf_rtn(h0[((size_t)layer * BBS + chunk * BC + idx / HH) * HH + idx % HH]);
    if (grp == 0) hbufL[0][idx / HH][idx % HH] = v;
    else          hbufU[1][idx / HH][idx % HH] = v;
  }

  // ---- B-fragments: fused W = [Whh (k 0..99) ; Wih (k 128..227)],
  // SINGLE-PLANE RTN bf16. For layer 9, n==100 carries Wout in the Whh half.
  short8 Bf[8][2];
  #pragma unroll
  for (int kc = 0; kc < 8; ++kc) {
    #pragma unroll
    for (int ntl = 0; ntl < 2; ++ntl) {
      const int n = wave * 32 + ntl * 16 + lp;
      float wv[8];
      #pragma unroll
      for (int j = 0; j < 8; ++j) {
        const int k = kc * 32 + quad * 8 + j;
        float w = 0.f;
        if (kc < 4) {
          if (k < HH) {
            if (n < HH) w = Whh[(size_t)layer * HH * HH + n * HH + k];
            else if (n == 100 && layer == NL - 1) w = Wout[k];
          }
        } else {
          const int kk = k - 128;
          if (layer > 0 && kk >= 0 && kk < HH && n < HH)
            w = Wih[(size_t)(layer - 1) * HH * HH + n * HH + kk];
        }
        wv[j] = w;
      }
      __attribute__((ext_vector_type(4))) unsigned int p1;
      #pragma unroll
      for (int j2 = 0; j2 < 4; ++j2)
        p1[j2] = (unsigned)bf_rtn(wv[2 * j2]) | ((unsigned)bf_rtn(wv[2 * j2 + 1]) << 16);
      Bf[kc][ntl] = __builtin_bit_cast(short8, p1);
    }
  }

  // ---- flags / ring pointers: 4 cross-pair interfaces, R19 protocol ----
  const bool is_cons = (grp == 0 && pair > 0);            // lower consumes ring
  const bool is_prod = (grp == 1 && pair < NPAIR - 1);    // upper produces ring
  int* prog_in  = is_cons ? wsi + flag_idx(pair - 1, chunk)        : nullptr;
  int* cons_in  = is_cons ? wsi + 8192 + flag_idx(pair - 1, chunk) : nullptr;
  int* prog_out = is_prod ? wsi + flag_idx(pair, chunk)            : nullptr;
  int* cons_out = is_prod ? wsi + 8192 + flag_idx(pair, chunk)     : nullptr;
  unsigned short* ring_in  = is_cons ? ring + (size_t)((pair - 1) * NB + chunk) * RDv * SLOTS : nullptr;
  unsigned short* ring_out = is_prod ? ring + (size_t)(pair * NB + chunk) * RDv * SLOTS       : nullptr;

  const int jcv[2] = { wave * 32 + lp, wave * 32 + 16 + lp };   // C columns
  const float br[2]  = { biasS[grp][jcv[0]], biasS[grp][jcv[1]] };
  const float w0r[2] = { wi0s[jcv[0]], wi0s[jcv[1]] };
  const float boutv = bout[0];

  f32x4 hreg[2] = {};        // my h(t) fp32 (h_final exactness)
  float px = 0.f;
  const int srow = wtid >> 4, scol = (wtid & 15) * 8;   // staging coords

  // ---- prologue: slot-0 wait + exposed staging (once) ----
  if (tid == 0 && is_cons) {
    while (__hip_atomic_load(prog_in, __ATOMIC_RELAXED, __HIP_MEMORY_SCOPE_AGENT) < Kv)
      __builtin_amdgcn_s_sleep(1);
    (void)__hip_atomic_load(prog_in, __ATOMIC_ACQUIRE, __HIP_MEMORY_SCOPE_AGENT);
  }
  ctl_barrier();
  if (is_cons) {
    u32x4 g = *(const u32x4*)(ring_in + wtid * 8);   // slot 0
    *(u32x4*)&ibufL[0][srow][scol] = g;
  }
  if (grp == 0 && pair == 0 && wtid < BC)
    xin[0][wtid] = x[(size_t)(chunk * BC + wtid) * TTS];
  __syncthreads();

  for (int s = 0; s <= TTS; ++s) {
    const int par = s & 1, nxt = par ^ 1;
    const bool active = (grp == 0) ? (s < TTS) : (s >= 1);
    const int t = (grp == 0) ? s : s - 1;          // my timestep this step
    const bool preb = ((s & Km) == Km) && (s + 1 < TTS);   // pre-boundary
    const bool upub = (s >= 1) && ((s & Km) == 0);         // publish steps

    // ---- pre-boundary: flag waits for batch [s+1, s+1+K) ----
    if (preb) {
      if (tid == 0 && is_cons) {
        while (__hip_atomic_load(prog_in, __ATOMIC_RELAXED, __HIP_MEMORY_SCOPE_AGENT) < s + 1 + Kv)
          __builtin_amdgcn_s_sleep(1);
        (void)__hip_atomic_load(prog_in, __ATOMIC_ACQUIRE, __HIP_MEMORY_SCOPE_AGENT);
      }
      if (tid == 256 && is_prod && s + 1 + Kv > RDv) {
        while (__hip_atomic_load(cons_out, __ATOMIC_RELAXED, __HIP_MEMORY_SCOPE_AGENT) < s + 1 + Kv - RDv)
          __builtin_amdgcn_s_sleep(1);
      }
      ctl_barrier();
    }

    // ---- producer deferred ring store: slot s-2 from SETTLED hbufU[par] ----
    if (is_prod && s >= 2 && ((s - 1) & Km) != 0) {
      u32x4 v = *(const u32x4*)&hbufU[par][srow][scol];
      *(u32x4*)(ring_out + (size_t)((s - 2) & RDm) * SLOTS + wtid * 8) = v;
    }

    // ---- prefetch load: slot s+1 -> regs (staged into ibufL[nxt] late) ----
    u32x4 pv = {};
    bool pre = false;
    if (is_cons && s + 1 < TTS) {
      pv = *(const u32x4*)(ring_in + (size_t)((s + 1) & RDm) * SLOTS + wtid * 8);
      pre = true;
    }
    if (grp == 0 && pair == 0 && s + 1 < TTS && wtid < BC)
      px = x[(size_t)(chunk * BC + wtid) * TTS + (s + 1)];

    if (active) {
      // ---- A-fragments: hoisted LDS reads ----
      const unsigned short (*myH)[HSS] = (grp == 0) ? hbufL[par] : hbufU[par];
      const unsigned short (*myI)[HSS] = (grp == 0) ? ibufL[par] : hbufL[par];
      short8 Ah[4], AiS[4];
      #pragma unroll
      for (int kc = 0; kc < 4; ++kc)
        Ah[kc] = *(const short8*)&myH[lp][kc * 32 + quad * 8];
      const bool has_in = (grp == 1) || (pair > 0);
      if (has_in) {
        #pragma unroll
        for (int kc = 0; kc < 4; ++kc)
          AiS[kc] = *(const short8*)&myI[lp][kc * 32 + quad * 8];
      } else {
        #pragma unroll
        for (int kc = 0; kc < 4; ++kc) AiS[kc] = short8{};
      }

      // ---- MFMA: single-plane, bias pre-loaded in a1; input-term first ----
      f32x4 a1[2], c1[2] = {};
      #pragma unroll
      for (int ntl = 0; ntl < 2; ++ntl)
        a1[ntl] = (f32x4){br[ntl], br[ntl], br[ntl], br[ntl]};
      if (has_in) {
        #pragma unroll
        for (int kc = 0; kc < 4; ++kc) {
          #pragma unroll
          for (int ntl = 0; ntl < 2; ++ntl)
            c1[ntl] = __builtin_amdgcn_mfma_f32_16x16x32_bf16(AiS[kc], Bf[kc + 4][ntl], c1[ntl], 0, 0, 0);
        }
      }
      #pragma unroll
      for (int kc = 0; kc < 4; ++kc) {
        #pragma unroll
        for (int ntl = 0; ntl < 2; ++ntl)
          a1[ntl] = __builtin_amdgcn_mfma_f32_16x16x32_bf16(Ah[kc], Bf[kc][ntl], a1[ntl], 0, 0, 0);
      }

      // ---- epilogue: merge, (+x*w0), tanh, pack bf16, write [nxt] ----
      unsigned short (*myHn)[HSS] = (grp == 0) ? hbufL[nxt] : hbufU[nxt];
      #pragma unroll
      for (int ntl = 0; ntl < 2; ++ntl) {
        f32x4 sum = a1[ntl] + c1[ntl];
        #pragma unroll
        for (int r = 0; r < 4; ++r) {
          const int m = quad * 4 + r;
          float v = sum[r];
          if (layer == 0) v += xin[par][m] * w0r[ntl];
          if (is_l9 && jcv[ntl] == 100) {
            if (s >= 2)
              out[(size_t)(chunk * BC + m) * TTS + (s - 2)] = v;  // bias==bout
          } else {
            float h = fast_tanh(v);
            hreg[ntl][r] = h;
            if (jcv[ntl] < HH) myHn[m][jcv[ntl]] = bf_rtn(h);
          }
        }
      }

      if (t == TTS - 1) {   // final hidden state, fp32-exact from registers
        #pragma unroll
        for (int ntl = 0; ntl < 2; ++ntl)
          if (jcv[ntl] < HH)
            #pragma unroll
            for (int r = 0; r < 4; ++r)
              out[(size_t)BBS * TTS +
                  ((size_t)layer * BBS + chunk * BC + quad * 4 + r) * HH + jcv[ntl]] =
                  hreg[ntl][r];
      }
    }

    // ---- stage prefetched slot s+1 into ibufL[nxt] (one b128 write) ----
    if (pre) *(u32x4*)&ibufL[nxt][srow][scol] = pv;
    if (grp == 0 && pair == 0 && s + 1 < TTS && wtid < BC) xin[nxt][wtid] = px;

    // ---- end-of-step barrier (+ batch-last store & publish at upub) ----
    if (upub) {
      lds_barrier();           // settle hbufU[nxt] for the in-step store
      if (is_prod) {           // batch-last slot s-1, coalesced from LDS
        u32x4 v = *(const u32x4*)&hbufU[nxt][srow][scol];
        *(u32x4*)(ring_out + (size_t)((s - 1) & RDm) * SLOTS + wtid * 8) = v;
      }
      __syncthreads();         // full drain: all ring stores visible pre-flag
      if (tid == 256 && is_prod)
        __hip_atomic_store(prog_out, s, __ATOMIC_RELEASE, __HIP_MEMORY_SCOPE_AGENT);
      if (tid == 0 && is_cons)
        __hip_atomic_store(cons_in, s, __ATOMIC_RELAXED, __HIP_MEMORY_SCOPE_AGENT);
    } else {
      lds_barrier();
    }
  }

  // final output out(TTS-1) = h9(TTS-1)·wout + bout: one-time serial dot
  if (is_l9) {
    const int b = wtid >> 4, seg = wtid & 15;
    float sacc = 0.f;
    #pragma unroll
    for (int jj = 0; jj < 7; ++jj) {
      const int j = seg * 7 + jj;
      if (j < HH) {
        float h = __uint_as_float((unsigned)hbufU[1][b][j] << 16);
        sacc += h * wouts[j];
      }
    }
    sacc += __shfl_xor(sacc, 1, 16);
    sacc += __shfl_xor(sacc, 2, 16);
    sacc += __shfl_xor(sacc, 4, 16);
    sacc += __shfl_xor(sacc, 8, 16);
    if ((wtid & 15) == 0)
      out[(size_t)(chunk * BC + b) * TTS + (TTS - 1)] = sacc + boutv;
  }
}

extern "C" void kernel_launch(void* const* d_in, const int* in_sizes, int n_in,
                              void* d_out, int out_size, void* d_ws, size_t ws_size,
                              hipStream_t stream) {
  const float* x    = (const float*)d_in[0];
  const float* h0   = (const float*)d_in[1];
  const float* Wih0 = (const float*)d_in[2];
  const float* Wih  = (const float*)d_in[3];
  const float* Whh  = (const float*)d_in[4];
  const float* bih  = (const float*)d_in[5];
  const float* bhh  = (const float*)d_in[6];
  const float* Wout = (const float*)d_in[7];
  const float* bout = (const float*)d_in[8];
  float* out = (float*)d_out;

  int* wsi = (int*)d_ws;
  unsigned short* ring = (unsigned short*)((char*)d_ws + 65536);

  // m-major bf16 ring: bytes = 4*32 * RD * 4096 (RD=32 -> 16.8MB).
  const size_t slot_bytes = (size_t)SLOTS * 2;   // 4096
  int RDv = 32;
  while (RDv > 2 && 65536 + (size_t)NIF * NB * RDv * slot_bytes > ws_size)
    RDv >>= 1;
  // DEADLOCK-FREE: skewed pipeline + boundary pipelining needs 2K+1 < RD.
  int Kv = RDv / 4;
  if (Kv < 1) Kv = 1;

  hipLaunchKernelGGL(init_ws_kernel, dim3(64), dim3(256), 0, stream, wsi);
  hipLaunchKernelGGL(rnn_pipe, dim3(NPAIR * NB), dim3(NT), 0, stream,
                     x, h0, Wih0, Wih, Whh, bih, bhh, Wout, bout, out, ring, wsi,
                     Kv, RDv);
}